// Round 11
// baseline (323.029 us; speedup 1.0000x reference)
//
#include <hip/hip_runtime.h>
#include <hip/hip_bf16.h>

#define E_    8
#define D_    2048
#define H_    1024
#define T_    2048   // B*L tokens
#define BK    64

using u16   = unsigned short;
using s16x8 = __attribute__((ext_vector_type(8))) short;
using f32x4 = __attribute__((ext_vector_type(4))) float;

#define WAITVM0 asm volatile("s_waitcnt vmcnt(0)" ::: "memory")

__device__ __forceinline__ short f2bf(float f) {
  __hip_bfloat16 h = __float2bfloat16(f);          // HW v_cvt (RNE)
  return __builtin_bit_cast(short, h);
}
__device__ __forceinline__ s16x8 cvt8(f32x4 a, f32x4 b) {
  s16x8 o;
  o[0]=f2bf(a.x); o[1]=f2bf(a.y); o[2]=f2bf(a.z); o[3]=f2bf(a.w);
  o[4]=f2bf(b.x); o[5]=f2bf(b.y); o[6]=f2bf(b.z); o[7]=f2bf(b.w);
  return o;
}
// swizzled LDS slot (elem index) for (row, 8-elem chunk) in a [*][64] bf16 tile
__device__ __forceinline__ int slot(int r, int c) { return r * 64 + ((c ^ (r & 7)) << 3); }

__device__ __forceinline__ void gload16(const void* g, void* l) {
  __builtin_amdgcn_global_load_lds((const __attribute__((address_space(1))) void*)g,
                                   (__attribute__((address_space(3))) void*)l, 16, 0, 0);
}

// find (e, mt, Ne) for linear m-tile index ml (BM=128); registers only
#define FIND_EXPERT(ml, cnt, e, mt, Ne)                        \
  { int b_ = 0;                                                \
    _Pragma("unroll")                                          \
    for (int i_ = 0; i_ < E_; ++i_) {                          \
      int ti_ = (cnt[i_] + 127) >> 7;                          \
      if ((ml) >= b_ && (ml) < b_ + ti_) {                     \
        e = i_; mt = (ml) - b_; Ne = cnt[i_]; }                \
      b_ += ti_; } }

// ---------------- workspace layout (bytes) ----------------
// xb     : T*D bf16     =  8,388,608  @ 0
// a_buf  : E*T*H bf16   = 33,554,432  @ 8,388,608
// lists  : E*T int      =     65,536  @ 41,943,040
// gates  : T*K f32      =     16,384  @ 42,008,576
// counts : E int        =         32  @ 42,024,960
// q1,q2  : 8+8 int      =         64  @ 42,024,992   (dynamic tile queues)

// one block per token: logits, top-2 + softmax, lists, x -> bf16, out = bias
__global__ __launch_bounds__(256) void router_kernel(
    const float* __restrict__ x, const float* __restrict__ wg,
    const float* __restrict__ bias,
    u16* __restrict__ xb, int* __restrict__ lists, float* __restrict__ gates,
    int* __restrict__ counts, float* __restrict__ out)
{
  int t = blockIdx.x;
  int tid = threadIdx.x;

  {
    const float* bp = bias + tid * 8;
    f32x4 b0 = *(const f32x4*)(bp), b1 = *(const f32x4*)(bp + 4);
    *(f32x4*)(out + (size_t)t * D_ + tid * 8)     = b0;
    *(f32x4*)(out + (size_t)t * D_ + tid * 8 + 4) = b1;
    if (t == 0 && tid == 0) out[(size_t)T_ * D_] = 0.0f;   // router aux loss
  }

  const float* xr = x + (size_t)t * D_;
  float acc[E_];
#pragma unroll
  for (int e = 0; e < E_; ++e) acc[e] = 0.f;
#pragma unroll
  for (int i = 0; i < D_ / 256; ++i) {
    int d = tid + 256 * i;
    float xv = xr[d];
    xb[(size_t)t * D_ + d] = (u16)f2bf(xv);
#pragma unroll
    for (int e = 0; e < E_; ++e) acc[e] += xv * wg[e * D_ + d];
  }
#pragma unroll
  for (int off = 32; off >= 1; off >>= 1)
#pragma unroll
    for (int e = 0; e < E_; ++e) acc[e] += __shfl_down(acc[e], off);

  __shared__ float red[4][E_];
  int w = tid >> 6, lane = tid & 63;
  if (lane == 0)
#pragma unroll
    for (int e = 0; e < E_; ++e) red[w][e] = acc[e];
  __syncthreads();
  if (tid == 0) {
    float v0 = -1e30f, v1 = -1e30f; int e0 = 0, e1 = 0;
#pragma unroll
    for (int e = 0; e < E_; ++e) {
      float v = red[0][e] + red[1][e] + red[2][e] + red[3][e];
      if (v > v0)      { v1 = v0; e1 = e0; v0 = v; e0 = e; }
      else if (v > v1) { v1 = v;  e1 = e; }
    }
    float g1 = expf(v1 - v0);
    float inv = 1.f / (1.f + g1);
    float g0 = inv; g1 *= inv;
    int s0 = atomicAdd(&counts[e0], 1);
    lists[e0 * T_ + s0] = t * 2 + 0;
    gates[t * 2 + 0] = g0;
    int s1 = atomicAdd(&counts[e1], 1);
    lists[e1 * T_ + s1] = t * 2 + 1;
    gates[t * 2 + 1] = g1;
  }
}

// grouped GEMM1 + SiLU-GLU. Tile 128 token-rows x 128 B-rows (64 h-cols,
// h1/h2 interleaved per 16). 4 waves (2m x 2n) of 64x64 -> 16 MFMA per
// 8 ds_read. A bf16 via gload_lds (pre-swizzled src); B fp32 reg-staged +
// HW cvt. Dynamic per-XCD tile queue (no quantization cliff).
__global__ __launch_bounds__(256, 2) void gemm1_kernel(
    const u16* __restrict__ xb, const float* __restrict__ w_in,
    const int* __restrict__ lists, const int* __restrict__ counts,
    u16* __restrict__ a_buf, int* __restrict__ q)
{
  __shared__ __align__(16) u16 As[2][128 * 64];   // 32 KB
  __shared__ __align__(16) u16 Bs[2][128 * 64];   // 32 KB -> 64 KB, 2 blocks/CU
  __shared__ int s_sl;

  int cnt[E_];
#pragma unroll
  for (int i = 0; i < E_; ++i) cnt[i] = counts[i];
  int mt_total = 0;
#pragma unroll
  for (int i = 0; i < E_; ++i) mt_total += (cnt[i] + 127) >> 7;
  int total = ((mt_total + 1) >> 1) * 32;         // PAIR-PADDED tile space (R10 bug fix)
  int chunk = (total + 7) >> 3;

  int tid = threadIdx.x, w = tid >> 6, lane = tid & 63;
  int swzc = ((lane & 7) ^ (lane >> 3)) * 8;      // pre-swizzled A source chunk
  int wr = (w >> 1) * 64, wc = (w & 1) * 64, lrow = lane & 15, g = lane >> 4;
  int lcol = lane & 15, lr4 = (lane >> 4) * 4;
  int br = tid >> 1, bhalf = (tid & 1) * 32, bj0 = (tid & 1) * 4;
  int xcd = blockIdx.x & 7;

  for (;;) {
    __syncthreads();                              // protects s_sl + LDS reuse
    if (tid == 0) s_sl = atomicAdd(&q[xcd], 1);
    __syncthreads();
    int sl = s_sl;
    if (sl >= chunk) break;
    int t = xcd * chunk + sl;
    if (t >= total) break;
    int p = t >> 5, qq = t & 31;
    int ml = p * 2 + (qq & 1), n = qq >> 1;       // pair-interleave: B reuse in L2
    if (ml >= mt_total) continue;                 // pad tile (odd mt_total)
    int e = 0, mt = 0, Ne = 0;
    FIND_EXPERT(ml, cnt, e, mt, Ne);

    const u16* ap[4];                             // A: rows w*32 + i*8 + (lane>>3)
#pragma unroll
    for (int i = 0; i < 4; ++i) {
      int gr = mt * 128 + w * 32 + i * 8 + (lane >> 3);
      if (gr >= Ne) gr = Ne - 1;
      ap[i] = xb + (size_t)(lists[e * T_ + gr] >> 1) * D_ + swzc;
    }
    // B row br (0..127) -> w_in row: h-col n*64 + (br>>5)*16 + (br&15), mat (br>>4)&1
    int o = n * 64 + ((br >> 4) & 1) * H_ + (br >> 5) * 16 + (br & 15);
    const float* bp = w_in + (size_t)e * (2 * H_) * D_ + (size_t)o * D_ + bhalf;

    f32x4 acc[4][4];
#pragma unroll
    for (int m = 0; m < 4; ++m)
#pragma unroll
      for (int nn = 0; nn < 4; ++nn) acc[m][nn] = (f32x4){0.f, 0.f, 0.f, 0.f};
    f32x4 bl[8];

    // prologue: stage kt=0 into buf 0
#pragma unroll
    for (int i = 0; i < 4; ++i) gload16(ap[i], &As[0][(w * 32 + i * 8) * 64]);
#pragma unroll
    for (int j = 0; j < 8; ++j) bl[j] = *(const f32x4*)(bp + j * 4);
    WAITVM0;
#pragma unroll
    for (int j = 0; j < 4; ++j)
      *(s16x8*)(&Bs[0][slot(br, bj0 + j)]) = cvt8(bl[2 * j], bl[2 * j + 1]);
    __syncthreads();

    const int NT = D_ / BK;                       // 32
    for (int kt = 0; kt < NT; ++kt) {
      int cur = kt & 1;
      if (kt + 1 < NT) {
        int k = (kt + 1) * BK;
#pragma unroll
        for (int i = 0; i < 4; ++i) gload16(ap[i] + k, &As[cur ^ 1][(w * 32 + i * 8) * 64]);
#pragma unroll
        for (int j = 0; j < 8; ++j) bl[j] = *(const f32x4*)(bp + k + j * 4);
      }
#pragma unroll
      for (int ks = 0; ks < 2; ++ks) {
        int ch = ks * 4 + g;
        s16x8 af[4], bf[4];
#pragma unroll
        for (int m = 0; m < 4; ++m) af[m] = *(const s16x8*)(&As[cur][slot(wr + m * 16 + lrow, ch)]);
#pragma unroll
        for (int nn = 0; nn < 4; ++nn) bf[nn] = *(const s16x8*)(&Bs[cur][slot(wc + nn * 16 + lrow, ch)]);
#pragma unroll
        for (int m = 0; m < 4; ++m)
#pragma unroll
          for (int nn = 0; nn < 4; ++nn)
            acc[m][nn] = __builtin_amdgcn_mfma_f32_16x16x32_bf16(af[m], bf[nn], acc[m][nn], 0, 0, 0);
      }
      if (kt + 1 < NT) {
        WAITVM0;                                  // A gloads + B reg loads landed
#pragma unroll
        for (int j = 0; j < 4; ++j)
          *(s16x8*)(&Bs[cur ^ 1][slot(br, bj0 + j)]) = cvt8(bl[2 * j], bl[2 * j + 1]);
        __syncthreads();
      }
    }
    // epilogue: frag pairs (2p2, 2p2+1) = (h1, h2) same lane -> a = silu(h1)*h2
#pragma unroll
    for (int m = 0; m < 4; ++m)
#pragma unroll
      for (int q2 = 0; q2 < 4; ++q2) {
        int row = mt * 128 + wr + m * 16 + lr4 + q2;
        if (row < Ne) {
#pragma unroll
          for (int p2 = 0; p2 < 2; ++p2) {
            float h1 = acc[m][2 * p2][q2], h2 = acc[m][2 * p2 + 1][q2];
            float a = (h1 / (1.f + __expf(-h1))) * h2;
            int col = n * 64 + ((w & 1) * 2 + p2) * 16 + lcol;
            a_buf[((size_t)e * T_ + row) * H_ + col] = (u16)f2bf(a);
          }
        }
      }
  }
}

// grouped GEMM2: out[t] += gate * (a_row . w_out[e]^T). Tile 128 x 128 d-cols,
// 4 waves of 64x64, K=1024. Same staging scheme + dynamic queue.
__global__ __launch_bounds__(256, 2) void gemm2_kernel(
    const u16* __restrict__ a_buf, const float* __restrict__ w_out,
    const int* __restrict__ lists, const int* __restrict__ counts,
    const float* __restrict__ gates, float* __restrict__ out, int* __restrict__ q)
{
  __shared__ __align__(16) u16 As[2][128 * 64];
  __shared__ __align__(16) u16 Bs[2][128 * 64];
  __shared__ int s_sl;

  int cnt[E_];
#pragma unroll
  for (int i = 0; i < E_; ++i) cnt[i] = counts[i];
  int mt_total = 0;
#pragma unroll
  for (int i = 0; i < E_; ++i) mt_total += (cnt[i] + 127) >> 7;
  int total = ((mt_total + 1) >> 1) * 32;         // PAIR-PADDED tile space (R10 bug fix)
  int chunk = (total + 7) >> 3;

  int tid = threadIdx.x, w = tid >> 6, lane = tid & 63;
  int swzc = ((lane & 7) ^ (lane >> 3)) * 8;
  int wr = (w >> 1) * 64, wc = (w & 1) * 64, lrow = lane & 15, g = lane >> 4;
  int lcol = lane & 15, lr4 = (lane >> 4) * 4;
  int br = tid >> 1, bhalf = (tid & 1) * 32, bj0 = (tid & 1) * 4;
  int xcd = blockIdx.x & 7;

  for (;;) {
    __syncthreads();
    if (tid == 0) s_sl = atomicAdd(&q[xcd], 1);
    __syncthreads();
    int sl = s_sl;
    if (sl >= chunk) break;
    int t = xcd * chunk + sl;
    if (t >= total) break;
    int p = t >> 5, qq = t & 31;
    int ml = p * 2 + (qq & 1), n = qq >> 1;
    if (ml >= mt_total) continue;
    int e = 0, mt = 0, Ne = 0;
    FIND_EXPERT(ml, cnt, e, mt, Ne);

    const u16* ap[4];
#pragma unroll
    for (int i = 0; i < 4; ++i) {
      int gr = mt * 128 + w * 32 + i * 8 + (lane >> 3);
      if (gr >= Ne) gr = Ne - 1;
      ap[i] = a_buf + ((size_t)e * T_ + gr) * H_ + swzc;
    }
    const float* bp = w_out + (size_t)e * D_ * H_ + (size_t)(n * 128 + br) * H_ + bhalf;

    f32x4 acc[4][4];
#pragma unroll
    for (int m = 0; m < 4; ++m)
#pragma unroll
      for (int nn = 0; nn < 4; ++nn) acc[m][nn] = (f32x4){0.f, 0.f, 0.f, 0.f};
    f32x4 bl[8];

#pragma unroll
    for (int i = 0; i < 4; ++i) gload16(ap[i], &As[0][(w * 32 + i * 8) * 64]);
#pragma unroll
    for (int j = 0; j < 8; ++j) bl[j] = *(const f32x4*)(bp + j * 4);
    WAITVM0;
#pragma unroll
    for (int j = 0; j < 4; ++j)
      *(s16x8*)(&Bs[0][slot(br, bj0 + j)]) = cvt8(bl[2 * j], bl[2 * j + 1]);
    __syncthreads();

    const int NT = H_ / BK;                       // 16
    for (int kt = 0; kt < NT; ++kt) {
      int cur = kt & 1;
      if (kt + 1 < NT) {
        int k = (kt + 1) * BK;
#pragma unroll
        for (int i = 0; i < 4; ++i) gload16(ap[i] + k, &As[cur ^ 1][(w * 32 + i * 8) * 64]);
#pragma unroll
        for (int j = 0; j < 8; ++j) bl[j] = *(const f32x4*)(bp + k + j * 4);
      }
#pragma unroll
      for (int ks = 0; ks < 2; ++ks) {
        int ch = ks * 4 + g;
        s16x8 af[4], bf[4];
#pragma unroll
        for (int m = 0; m < 4; ++m) af[m] = *(const s16x8*)(&As[cur][slot(wr + m * 16 + lrow, ch)]);
#pragma unroll
        for (int nn = 0; nn < 4; ++nn) bf[nn] = *(const s16x8*)(&Bs[cur][slot(wc + nn * 16 + lrow, ch)]);
#pragma unroll
        for (int m = 0; m < 4; ++m)
#pragma unroll
          for (int nn = 0; nn < 4; ++nn)
            acc[m][nn] = __builtin_amdgcn_mfma_f32_16x16x32_bf16(af[m], bf[nn], acc[m][nn], 0, 0, 0);
      }
      if (kt + 1 < NT) {
        WAITVM0;
#pragma unroll
        for (int j = 0; j < 4; ++j)
          *(s16x8*)(&Bs[cur ^ 1][slot(br, bj0 + j)]) = cvt8(bl[2 * j], bl[2 * j + 1]);
        __syncthreads();
      }
    }
    // epilogue: atomic accumulate (bias pre-filled by router)
#pragma unroll
    for (int m = 0; m < 4; ++m)
#pragma unroll
      for (int q2 = 0; q2 < 4; ++q2) {
        int row = mt * 128 + wr + m * 16 + lr4 + q2;
        if (row < Ne) {
          int pidx = lists[e * T_ + row];
          float gt = gates[pidx];
          int tok = pidx >> 1;
#pragma unroll
          for (int nn = 0; nn < 4; ++nn) {
            int col = n * 128 + wc + nn * 16 + lcol;
            atomicAdd(&out[(size_t)tok * D_ + col], gt * acc[m][nn][q2]);
          }
        }
      }
  }
}

extern "C" void kernel_launch(void* const* d_in, const int* in_sizes, int n_in,
                              void* d_out, int out_size, void* d_ws, size_t ws_size,
                              hipStream_t stream)
{
  const float* x      = (const float*)d_in[0];
  const float* w_gate = (const float*)d_in[1];
  const float* w_in   = (const float*)d_in[2];
  const float* w_out  = (const float*)d_in[3];
  const float* bias   = (const float*)d_in[4];
  float* out = (float*)d_out;

  char* ws = (char*)d_ws;
  u16*   xb     = (u16*)(ws);
  u16*   a_buf  = (u16*)(ws + 8388608);
  int*   lists  = (int*)(ws + 41943040);
  float* gates  = (float*)(ws + 42008576);
  int*   counts = (int*)(ws + 42024960);
  int*   q1     = (int*)(ws + 42024992);
  int*   q2     = (int*)(ws + 42025024);

  hipMemsetAsync(counts, 0, 96, stream);          // counts + q1 + q2
  router_kernel<<<T_, 256, 0, stream>>>(x, w_gate, bias, xb, lists, gates, counts, out);
  gemm1_kernel<<<512, 256, 0, stream>>>(xb, w_in, lists, counts, a_buf, q1);
  gemm2_kernel<<<512, 256, 0, stream>>>(a_buf, w_out, lists, counts, gates, out, q2);
}

// Round 12
// 297.946 us; speedup vs baseline: 1.0842x; 1.0842x over previous
//
#include <hip/hip_runtime.h>
#include <hip/hip_bf16.h>

#define E_    8
#define D_    2048
#define H_    1024
#define T_    2048   // B*L tokens
#define BK    64

using u16   = unsigned short;
using s16x8 = __attribute__((ext_vector_type(8))) short;
using f32x4 = __attribute__((ext_vector_type(4))) float;

__device__ __forceinline__ short f2bf(float f) {
  __hip_bfloat16 h = __float2bfloat16(f);          // HW v_cvt (RNE)
  return __builtin_bit_cast(short, h);
}
__device__ __forceinline__ s16x8 cvt8(f32x4 a, f32x4 b) {
  s16x8 o;
  o[0]=f2bf(a.x); o[1]=f2bf(a.y); o[2]=f2bf(a.z); o[3]=f2bf(a.w);
  o[4]=f2bf(b.x); o[5]=f2bf(b.y); o[6]=f2bf(b.z); o[7]=f2bf(b.w);
  return o;
}
// swizzled LDS slot (elem index) for (row, 8-elem chunk) in a [*][64] bf16 tile
__device__ __forceinline__ int slot(int r, int c) { return r * 64 + ((c ^ (r & 7)) << 3); }

__device__ __forceinline__ void gload16(const void* g, void* l) {
  __builtin_amdgcn_global_load_lds((const __attribute__((address_space(1))) void*)g,
                                   (__attribute__((address_space(3))) void*)l, 16, 0, 0);
}

// ---------------- workspace layout (bytes) ----------------
// xb     : T*D bf16     =  8,388,608  @ 0
// a_buf  : E*T*H bf16   = 33,554,432  @ 8,388,608
// lists  : E*T int      =     65,536  @ 41,943,040
// gates  : T*K f32      =     16,384  @ 42,008,576
// counts : E int        =         32  @ 42,024,960

// one block per token: logits, top-2 + softmax, lists, x -> bf16, out = bias
__global__ __launch_bounds__(256) void router_kernel(
    const float* __restrict__ x, const float* __restrict__ wg,
    const float* __restrict__ bias,
    u16* __restrict__ xb, int* __restrict__ lists, float* __restrict__ gates,
    int* __restrict__ counts, float* __restrict__ out)
{
  int t = blockIdx.x;
  int tid = threadIdx.x;

  {
    const float* bp = bias + tid * 8;
    f32x4 b0 = *(const f32x4*)(bp), b1 = *(const f32x4*)(bp + 4);
    *(f32x4*)(out + (size_t)t * D_ + tid * 8)     = b0;
    *(f32x4*)(out + (size_t)t * D_ + tid * 8 + 4) = b1;
    if (t == 0 && tid == 0) out[(size_t)T_ * D_] = 0.0f;   // router aux loss
  }

  const float* xr = x + (size_t)t * D_;
  float acc[E_];
#pragma unroll
  for (int e = 0; e < E_; ++e) acc[e] = 0.f;
#pragma unroll
  for (int i = 0; i < D_ / 256; ++i) {
    int d = tid + 256 * i;
    float xv = xr[d];
    xb[(size_t)t * D_ + d] = (u16)f2bf(xv);
#pragma unroll
    for (int e = 0; e < E_; ++e) acc[e] += xv * wg[e * D_ + d];
  }
#pragma unroll
  for (int off = 32; off >= 1; off >>= 1)
#pragma unroll
    for (int e = 0; e < E_; ++e) acc[e] += __shfl_down(acc[e], off);

  __shared__ float red[4][E_];
  int w = tid >> 6, lane = tid & 63;
  if (lane == 0)
#pragma unroll
    for (int e = 0; e < E_; ++e) red[w][e] = acc[e];
  __syncthreads();
  if (tid == 0) {
    float v0 = -1e30f, v1 = -1e30f; int e0 = 0, e1 = 0;
#pragma unroll
    for (int e = 0; e < E_; ++e) {
      float v = red[0][e] + red[1][e] + red[2][e] + red[3][e];
      if (v > v0)      { v1 = v0; e1 = e0; v0 = v; e0 = e; }
      else if (v > v1) { v1 = v;  e1 = e; }
    }
    float g1 = expf(v1 - v0);
    float inv = 1.f / (1.f + g1);
    float g0 = inv; g1 *= inv;
    int s0 = atomicAdd(&counts[e0], 1);
    lists[e0 * T_ + s0] = t * 2 + 0;
    gates[t * 2 + 0] = g0;
    int s1 = atomicAdd(&counts[e1], 1);
    lists[e1 * T_ + s1] = t * 2 + 1;
    gates[t * 2 + 1] = g1;
  }
}

// grouped GEMM1 + SiLU-GLU with EXPERT-PER-XCD AFFINITY: expert e = bid&7 runs
// entirely on XCD e, so its w_in panel re-reads are served by the local L2
// (per-K-step working set ~600 KB << 4 MB). Tile 128 rows x 128 B-rows
// (64 h-cols, h1/h2 per 16). 4 waves (2m x 2n) of 64x64. 64 slots/XCD.
// A bf16 via gload_lds (pre-swizzled src); B fp32 -> reg -> HW cvt -> LDS.
__global__ __launch_bounds__(256, 2) void gemm1_kernel(
    const u16* __restrict__ xb, const float* __restrict__ w_in,
    const int* __restrict__ lists, const int* __restrict__ counts,
    u16* __restrict__ a_buf)
{
  __shared__ __align__(16) u16 As[2][128 * 64];   // 32 KB
  __shared__ __align__(16) u16 Bs[2][128 * 64];   // 32 KB -> 64 KB, 2 blocks/CU

  int e = blockIdx.x & 7, slot0 = blockIdx.x >> 3;     // expert == XCD
  int Ne = counts[e];
  int Nm = (Ne + 127) >> 7;
  int total = Nm * 16;                                 // 16 n-tiles of 64 h-cols

  int tid = threadIdx.x, w = tid >> 6, lane = tid & 63;
  int swzc = ((lane & 7) ^ (lane >> 3)) * 8;           // pre-swizzled A src chunk
  int wr = (w >> 1) * 64, wc = (w & 1) * 64, lrow = lane & 15, g = lane >> 4;
  int lcol = lane & 15, lr4 = (lane >> 4) * 4;
  int brow = tid >> 1, bj0 = (tid & 1) * 4;            // B: row, chunk base (4 chunks)

  for (int t = slot0; t < total; t += 64) {
    int mt = t >> 4, n = t & 15;                       // n fastest: A shared by 16 slots

    const u16* ap[4];                                  // A rows w*32 + i*8 + (lane>>3)
#pragma unroll
    for (int i = 0; i < 4; ++i) {
      int gr = mt * 128 + w * 32 + i * 8 + (lane >> 3);
      if (gr >= Ne) gr = Ne - 1;
      ap[i] = xb + (size_t)(lists[e * T_ + gr] >> 1) * D_ + swzc;
    }
    // B row r (0..127) -> w_in row: h-col n*64 + (r>>5)*16 + (r&15), mat (r>>4)&1
    int o = n * 64 + ((brow >> 4) & 1) * H_ + (brow >> 5) * 16 + (brow & 15);
    const float* bp = w_in + (size_t)e * (2 * H_) * D_ + (size_t)o * D_ + bj0 * 8;

    f32x4 acc[4][4];
#pragma unroll
    for (int m = 0; m < 4; ++m)
#pragma unroll
      for (int nn = 0; nn < 4; ++nn) acc[m][nn] = (f32x4){0.f, 0.f, 0.f, 0.f};
    f32x4 bl[8];

    // prologue: stage kt=0 into buf 0 (barrier drains gloads; compiler waits bl)
#pragma unroll
    for (int i = 0; i < 4; ++i) gload16(ap[i], &As[0][(w * 32 + i * 8) * 64]);
#pragma unroll
    for (int j = 0; j < 8; ++j) bl[j] = *(const f32x4*)(bp + j * 4);
#pragma unroll
    for (int j = 0; j < 4; ++j)
      *(s16x8*)(&Bs[0][slot(brow, bj0 + j)]) = cvt8(bl[2 * j], bl[2 * j + 1]);
    __syncthreads();

    const int NT = D_ / BK;                            // 32
    for (int kt = 0; kt < NT; ++kt) {
      int cur = kt & 1;
      if (kt + 1 < NT) {
        int k = (kt + 1) * BK;
#pragma unroll
        for (int i = 0; i < 4; ++i) gload16(ap[i] + k, &As[cur ^ 1][(w * 32 + i * 8) * 64]);
#pragma unroll
        for (int j = 0; j < 8; ++j) bl[j] = *(const f32x4*)(bp + k + j * 4);
      }
#pragma unroll
      for (int ks = 0; ks < 2; ++ks) {
        int ch = ks * 4 + g;
        s16x8 af[4], bf[4];
#pragma unroll
        for (int m = 0; m < 4; ++m) af[m] = *(const s16x8*)(&As[cur][slot(wr + m * 16 + lrow, ch)]);
#pragma unroll
        for (int nn = 0; nn < 4; ++nn) bf[nn] = *(const s16x8*)(&Bs[cur][slot(wc + nn * 16 + lrow, ch)]);
#pragma unroll
        for (int m = 0; m < 4; ++m)
#pragma unroll
          for (int nn = 0; nn < 4; ++nn)
            acc[m][nn] = __builtin_amdgcn_mfma_f32_16x16x32_bf16(af[m], bf[nn], acc[m][nn], 0, 0, 0);
      }
      if (kt + 1 < NT) {
#pragma unroll
        for (int j = 0; j < 4; ++j)                    // compiler-counted wait on bl only
          *(s16x8*)(&Bs[cur ^ 1][slot(brow, bj0 + j)]) = cvt8(bl[2 * j], bl[2 * j + 1]);
        __syncthreads();                               // drains A gloads too
      }
    }
    // epilogue: pairs (acc[m][2p], acc[m][2p+1]) = (h1, h2) -> a = silu(h1)*h2
#pragma unroll
    for (int m = 0; m < 4; ++m)
#pragma unroll
      for (int q2 = 0; q2 < 4; ++q2) {
        int row = mt * 128 + wr + m * 16 + lr4 + q2;
        if (row < Ne) {
#pragma unroll
          for (int p2 = 0; p2 < 2; ++p2) {
            float h1 = acc[m][2 * p2][q2], h2 = acc[m][2 * p2 + 1][q2];
            float a = (h1 / (1.f + __expf(-h1))) * h2;
            int col = n * 64 + (w & 1) * 32 + p2 * 16 + lcol;
            a_buf[((size_t)e * T_ + row) * H_ + col] = (u16)f2bf(a);
          }
        }
      }
  }
}

// grouped GEMM2: out[t] += gate * (a_row . w_out[e]^T), expert-per-XCD.
// Tile 128 rows x 128 d-cols, 4 waves of 64x64, K=1024, 64 slots/XCD.
__global__ __launch_bounds__(256, 2) void gemm2_kernel(
    const u16* __restrict__ a_buf, const float* __restrict__ w_out,
    const int* __restrict__ lists, const int* __restrict__ counts,
    const float* __restrict__ gates, float* __restrict__ out)
{
  __shared__ __align__(16) u16 As[2][128 * 64];
  __shared__ __align__(16) u16 Bs[2][128 * 64];

  int e = blockIdx.x & 7, slot0 = blockIdx.x >> 3;
  int Ne = counts[e];
  int Nm = (Ne + 127) >> 7;
  int total = Nm * 16;                                 // 16 n-tiles of 128 d-cols

  int tid = threadIdx.x, w = tid >> 6, lane = tid & 63;
  int swzc = ((lane & 7) ^ (lane >> 3)) * 8;
  int wr = (w >> 1) * 64, wc = (w & 1) * 64, lrow = lane & 15, g = lane >> 4;
  int lcol = lane & 15, lr4 = (lane >> 4) * 4;
  int brow = tid >> 1, bj0 = (tid & 1) * 4;

  for (int t = slot0; t < total; t += 64) {
    int mt = t >> 4, n = t & 15;

    const u16* ap[4];
#pragma unroll
    for (int i = 0; i < 4; ++i) {
      int gr = mt * 128 + w * 32 + i * 8 + (lane >> 3);
      if (gr >= Ne) gr = Ne - 1;
      ap[i] = a_buf + ((size_t)e * T_ + gr) * H_ + swzc;
    }
    const float* bp = w_out + (size_t)e * D_ * H_ + (size_t)(n * 128 + brow) * H_ + bj0 * 8;

    f32x4 acc[4][4];
#pragma unroll
    for (int m = 0; m < 4; ++m)
#pragma unroll
      for (int nn = 0; nn < 4; ++nn) acc[m][nn] = (f32x4){0.f, 0.f, 0.f, 0.f};
    f32x4 bl[8];

#pragma unroll
    for (int i = 0; i < 4; ++i) gload16(ap[i], &As[0][(w * 32 + i * 8) * 64]);
#pragma unroll
    for (int j = 0; j < 8; ++j) bl[j] = *(const f32x4*)(bp + j * 4);
#pragma unroll
    for (int j = 0; j < 4; ++j)
      *(s16x8*)(&Bs[0][slot(brow, bj0 + j)]) = cvt8(bl[2 * j], bl[2 * j + 1]);
    __syncthreads();

    const int NT = H_ / BK;                            // 16
    for (int kt = 0; kt < NT; ++kt) {
      int cur = kt & 1;
      if (kt + 1 < NT) {
        int k = (kt + 1) * BK;
#pragma unroll
        for (int i = 0; i < 4; ++i) gload16(ap[i] + k, &As[cur ^ 1][(w * 32 + i * 8) * 64]);
#pragma unroll
        for (int j = 0; j < 8; ++j) bl[j] = *(const f32x4*)(bp + k + j * 4);
      }
#pragma unroll
      for (int ks = 0; ks < 2; ++ks) {
        int ch = ks * 4 + g;
        s16x8 af[4], bf[4];
#pragma unroll
        for (int m = 0; m < 4; ++m) af[m] = *(const s16x8*)(&As[cur][slot(wr + m * 16 + lrow, ch)]);
#pragma unroll
        for (int nn = 0; nn < 4; ++nn) bf[nn] = *(const s16x8*)(&Bs[cur][slot(wc + nn * 16 + lrow, ch)]);
#pragma unroll
        for (int m = 0; m < 4; ++m)
#pragma unroll
          for (int nn = 0; nn < 4; ++nn)
            acc[m][nn] = __builtin_amdgcn_mfma_f32_16x16x32_bf16(af[m], bf[nn], acc[m][nn], 0, 0, 0);
      }
      if (kt + 1 < NT) {
#pragma unroll
        for (int j = 0; j < 4; ++j)
          *(s16x8*)(&Bs[cur ^ 1][slot(brow, bj0 + j)]) = cvt8(bl[2 * j], bl[2 * j + 1]);
        __syncthreads();
      }
    }
    // epilogue: atomic accumulate (bias pre-filled by router)
#pragma unroll
    for (int m = 0; m < 4; ++m)
#pragma unroll
      for (int q2 = 0; q2 < 4; ++q2) {
        int row = mt * 128 + wr + m * 16 + lr4 + q2;
        if (row < Ne) {
          int pidx = lists[e * T_ + row];
          float gt = gates[pidx];
          int tok = pidx >> 1;
#pragma unroll
          for (int nn = 0; nn < 4; ++nn) {
            int col = n * 128 + wc + nn * 16 + lcol;
            atomicAdd(&out[(size_t)tok * D_ + col], gt * acc[m][nn][q2]);
          }
        }
      }
  }
}

extern "C" void kernel_launch(void* const* d_in, const int* in_sizes, int n_in,
                              void* d_out, int out_size, void* d_ws, size_t ws_size,
                              hipStream_t stream)
{
  const float* x      = (const float*)d_in[0];
  const float* w_gate = (const float*)d_in[1];
  const float* w_in   = (const float*)d_in[2];
  const float* w_out  = (const float*)d_in[3];
  const float* bias   = (const float*)d_in[4];
  float* out = (float*)d_out;

  char* ws = (char*)d_ws;
  u16*   xb     = (u16*)(ws);
  u16*   a_buf  = (u16*)(ws + 8388608);
  int*   lists  = (int*)(ws + 41943040);
  float* gates  = (float*)(ws + 42008576);
  int*   counts = (int*)(ws + 42024960);

  hipMemsetAsync(counts, 0, 32, stream);
  router_kernel<<<T_, 256, 0, stream>>>(x, w_gate, bias, xb, lists, gates, counts, out);
  gemm1_kernel<<<512, 256, 0, stream>>>(xb, w_in, lists, counts, a_buf);
  gemm2_kernel<<<512, 256, 0, stream>>>(a_buf, w_out, lists, counts, gates, out);
}

// Round 13
// 247.510 us; speedup vs baseline: 1.3051x; 1.2038x over previous
//
#include <hip/hip_runtime.h>
#include <hip/hip_bf16.h>

#define E_    8
#define D_    2048
#define H_    1024
#define T_    2048   // B*L tokens
#define BK    64

using u16   = unsigned short;
using s16x8 = __attribute__((ext_vector_type(8))) short;
using f32x4 = __attribute__((ext_vector_type(4))) float;

#define WAITVM0 asm volatile("s_waitcnt vmcnt(0)" ::: "memory")

__device__ __forceinline__ short f2bf(float f) {
  __hip_bfloat16 h = __float2bfloat16(f);          // HW v_cvt (RNE)
  return __builtin_bit_cast(short, h);
}
// swizzled LDS slot (elem index) for (row, 8-elem chunk) in a [*][64] bf16 tile
__device__ __forceinline__ int slot(int r, int c) { return r * 64 + ((c ^ (r & 7)) << 3); }

__device__ __forceinline__ void gload16(const void* g, void* l) {
  __builtin_amdgcn_global_load_lds((const __attribute__((address_space(1))) void*)g,
                                   (__attribute__((address_space(3))) void*)l, 16, 0, 0);
}

// find (e, mt, Ne) for linear m-tile index ml (BM=128); registers only
#define FIND_EXPERT(ml, cnt, e, mt, Ne)                        \
  { int b_ = 0;                                                \
    _Pragma("unroll")                                          \
    for (int i_ = 0; i_ < E_; ++i_) {                          \
      int ti_ = (cnt[i_] + 127) >> 7;                          \
      if ((ml) >= b_ && (ml) < b_ + ti_) {                     \
        e = i_; mt = (ml) - b_; Ne = cnt[i_]; }                \
      b_ += ti_; } }

// ---------------- workspace layout (bytes) ----------------
// xb     : T*D bf16      =  8,388,608  @ 0
// a_buf  : E*T*H bf16    = 33,554,432  @ 8,388,608
// wb_in  : E*2H*D bf16   = 67,108,864  @ 41,943,040
// wb_out : E*D*H bf16    = 33,554,432  @ 109,051,904
// lists  : E*T int       =     65,536  @ 142,606,336
// gates  : T*K f32       =     16,384  @ 142,671,872
// counts : E int         =         32  @ 142,688,256

#define WIN_ELEMS  33554432   // E*2H*D
#define WOUT_ELEMS 16777216   // E*D*H

// high-ILP fp32->bf16 streaming convert: 4 independent 16B loads per iter
__global__ __launch_bounds__(256) void convert_kernel(
    const float* __restrict__ src, u16* __restrict__ dst, int n)
{
  int stride = gridDim.x * 256 * 16;
  for (int i = (blockIdx.x * 256 + threadIdx.x) * 16; i < n; i += stride) {
    f32x4 a0 = *(const f32x4*)(src + i);
    f32x4 a1 = *(const f32x4*)(src + i + 4);
    f32x4 a2 = *(const f32x4*)(src + i + 8);
    f32x4 a3 = *(const f32x4*)(src + i + 12);
    s16x8 o0, o1;
    o0[0]=f2bf(a0.x); o0[1]=f2bf(a0.y); o0[2]=f2bf(a0.z); o0[3]=f2bf(a0.w);
    o0[4]=f2bf(a1.x); o0[5]=f2bf(a1.y); o0[6]=f2bf(a1.z); o0[7]=f2bf(a1.w);
    o1[0]=f2bf(a2.x); o1[1]=f2bf(a2.y); o1[2]=f2bf(a2.z); o1[3]=f2bf(a2.w);
    o1[4]=f2bf(a3.x); o1[5]=f2bf(a3.y); o1[6]=f2bf(a3.z); o1[7]=f2bf(a3.w);
    *(s16x8*)(dst + i)     = o0;
    *(s16x8*)(dst + i + 8) = o1;
  }
}

// one block per token: logits, top-2 + softmax, lists, x -> bf16, out = bias
__global__ __launch_bounds__(256) void router_kernel(
    const float* __restrict__ x, const float* __restrict__ wg,
    const float* __restrict__ bias,
    u16* __restrict__ xb, int* __restrict__ lists, float* __restrict__ gates,
    int* __restrict__ counts, float* __restrict__ out)
{
  int t = blockIdx.x;
  int tid = threadIdx.x;

  {
    const float* bp = bias + tid * 8;
    f32x4 b0 = *(const f32x4*)(bp), b1 = *(const f32x4*)(bp + 4);
    *(f32x4*)(out + (size_t)t * D_ + tid * 8)     = b0;
    *(f32x4*)(out + (size_t)t * D_ + tid * 8 + 4) = b1;
    if (t == 0 && tid == 0) out[(size_t)T_ * D_] = 0.0f;   // router aux loss
  }

  const float* xr = x + (size_t)t * D_;
  float acc[E_];
#pragma unroll
  for (int e = 0; e < E_; ++e) acc[e] = 0.f;
#pragma unroll
  for (int i = 0; i < D_ / 256; ++i) {
    int d = tid + 256 * i;
    float xv = xr[d];
    xb[(size_t)t * D_ + d] = (u16)f2bf(xv);
#pragma unroll
    for (int e = 0; e < E_; ++e) acc[e] += xv * wg[e * D_ + d];
  }
#pragma unroll
  for (int off = 32; off >= 1; off >>= 1)
#pragma unroll
    for (int e = 0; e < E_; ++e) acc[e] += __shfl_down(acc[e], off);

  __shared__ float red[4][E_];
  int w = tid >> 6, lane = tid & 63;
  if (lane == 0)
#pragma unroll
    for (int e = 0; e < E_; ++e) red[w][e] = acc[e];
  __syncthreads();
  if (tid == 0) {
    float v0 = -1e30f, v1 = -1e30f; int e0 = 0, e1 = 0;
#pragma unroll
    for (int e = 0; e < E_; ++e) {
      float v = red[0][e] + red[1][e] + red[2][e] + red[3][e];
      if (v > v0)      { v1 = v0; e1 = e0; v0 = v; e0 = e; }
      else if (v > v1) { v1 = v;  e1 = e; }
    }
    float g1 = expf(v1 - v0);
    float inv = 1.f / (1.f + g1);
    float g0 = inv; g1 *= inv;
    int s0 = atomicAdd(&counts[e0], 1);
    lists[e0 * T_ + s0] = t * 2 + 0;
    gates[t * 2 + 0] = g0;
    int s1 = atomicAdd(&counts[e1], 1);
    lists[e1 * T_ + s1] = t * 2 + 1;
    gates[t * 2 + 1] = g1;
  }
}

// grouped GEMM1 + SiLU-GLU, all-bf16 gload_lds staging (R8 structure — best
// measured). Tile: 128 token-rows x 128 B-rows (64 h1 + 64 h2 -> 64 h-cols).
// 8 waves (2m x 4n), wave = 64 rows x 32 B-cols. 64 KB LDS -> 2 blocks/CU.
__global__ __launch_bounds__(512, 2) void gemm1_kernel(
    const u16* __restrict__ xb, const u16* __restrict__ wb_in,
    const int* __restrict__ lists, const int* __restrict__ counts,
    u16* __restrict__ a_buf)
{
  __shared__ __align__(16) u16 As[2][128 * 64];   // 32 KB
  __shared__ __align__(16) u16 Bs[2][128 * 64];   // 32 KB

  int cnt[E_];
#pragma unroll
  for (int i = 0; i < E_; ++i) cnt[i] = counts[i];
  int mt_total = 0;
#pragma unroll
  for (int i = 0; i < E_; ++i) mt_total += (cnt[i] + 127) >> 7;
  int total = mt_total * 16;                      // 16 n-tiles of 64 h-cols
  int chunk = (total + 7) >> 3;

  int tid = threadIdx.x, w = tid >> 6, lane = tid & 63;
  int swzc = ((lane & 7) ^ (lane >> 3)) * 8;      // pre-swizzled source chunk
  int wr = (w >> 2) * 64, wc = (w & 3) * 32, lrow = lane & 15, g = lane >> 4;
  int lcol = lane & 15, lr4 = (lane >> 4) * 4;
  int xcd = blockIdx.x & 7, bslot = blockIdx.x >> 3;

  for (int sl = bslot; sl < chunk; sl += 64) {
    int t = xcd * chunk + sl;
    if (t >= total) break;
    int ml = t >> 4, n = t & 15;
    int e = 0, mt = 0, Ne = 0;
    FIND_EXPERT(ml, cnt, e, mt, Ne);

    // A: 2 gloads/thread cover local rows w*8+(lane>>3) and +64
    const u16* ap[2];
#pragma unroll
    for (int i = 0; i < 2; ++i) {
      int gr = mt * 128 + w * 8 + i * 64 + (lane >> 3);
      if (gr >= Ne) gr = Ne - 1;
      ap[i] = xb + (size_t)(lists[e * T_ + gr] >> 1) * D_ + swzc;
    }
    // B: rows br -> wb_in row o = n*64 + mat*H + (br>>5)*16 + (br&15)
    const u16* bp[2];
#pragma unroll
    for (int i = 0; i < 2; ++i) {
      int br = w * 8 + i * 64 + (lane >> 3);
      int o = n * 64 + ((br >> 4) & 1) * H_ + (br >> 5) * 16 + (br & 15);
      bp[i] = wb_in + (size_t)e * (2 * H_) * D_ + (size_t)o * D_ + swzc;
    }

    f32x4 acc[4][2];
#pragma unroll
    for (int m = 0; m < 4; ++m) { acc[m][0] = (f32x4){0,0,0,0}; acc[m][1] = (f32x4){0,0,0,0}; }

    // prologue: stage kt=0 into buf 0
#pragma unroll
    for (int i = 0; i < 2; ++i) {
      gload16(ap[i], &As[0][(w * 8 + i * 64) * 64]);
      gload16(bp[i], &Bs[0][(w * 8 + i * 64) * 64]);
    }
    WAITVM0;
    __syncthreads();

    const int NT = D_ / BK;                        // 32
    for (int kt = 0; kt < NT; ++kt) {
      int cur = kt & 1;
      if (kt + 1 < NT) {
        int k = (kt + 1) * BK;
#pragma unroll
        for (int i = 0; i < 2; ++i) {
          gload16(ap[i] + k, &As[cur ^ 1][(w * 8 + i * 64) * 64]);
          gload16(bp[i] + k, &Bs[cur ^ 1][(w * 8 + i * 64) * 64]);
        }
      }
#pragma unroll
      for (int ks = 0; ks < 2; ++ks) {
        int ch = ks * 4 + g;
        s16x8 af[4], bf[2];
#pragma unroll
        for (int m = 0; m < 4; ++m) af[m] = *(const s16x8*)(&As[cur][slot(wr + m * 16 + lrow, ch)]);
#pragma unroll
        for (int s = 0; s < 2; ++s)  bf[s] = *(const s16x8*)(&Bs[cur][slot(wc + s * 16 + lrow, ch)]);
#pragma unroll
        for (int m = 0; m < 4; ++m)
#pragma unroll
          for (int s = 0; s < 2; ++s)
            acc[m][s] = __builtin_amdgcn_mfma_f32_16x16x32_bf16(af[m], bf[s], acc[m][s], 0, 0, 0);
      }
      WAITVM0;                                     // next-buf loads landed
      __syncthreads();
    }
    // epilogue: a = silu(h1)*h2 -> bf16; wave owns 64 rows x 16 h-cols
#pragma unroll
    for (int m = 0; m < 4; ++m)
#pragma unroll
      for (int q = 0; q < 4; ++q) {
        int row = mt * 128 + wr + m * 16 + lr4 + q;
        if (row < Ne) {
          float h1 = acc[m][0][q], h2 = acc[m][1][q];
          float a = (h1 / (1.f + __expf(-h1))) * h2;
          a_buf[((size_t)e * T_ + row) * H_ + n * 64 + (w & 3) * 16 + lcol] = (u16)f2bf(a);
        }
      }
  }
}

// grouped GEMM2: out[t] += gate * (a_row . wb_out^T), all-bf16 gloads.
// Tile: 128 rows x 128 d-cols, 8 waves (2m x 4n) of 64x32, 64 KB LDS.
__global__ __launch_bounds__(512, 2) void gemm2_kernel(
    const u16* __restrict__ a_buf, const u16* __restrict__ wb_out,
    const int* __restrict__ lists, const int* __restrict__ counts,
    const float* __restrict__ gates, float* __restrict__ out)
{
  __shared__ __align__(16) u16 As[2][128 * 64];
  __shared__ __align__(16) u16 Bs[2][128 * 64];

  int cnt[E_];
#pragma unroll
  for (int i = 0; i < E_; ++i) cnt[i] = counts[i];
  int mt_total = 0;
#pragma unroll
  for (int i = 0; i < E_; ++i) mt_total += (cnt[i] + 127) >> 7;
  int total = mt_total * 16;                      // 16 n-tiles of 128 d-cols
  int chunk = (total + 7) >> 3;

  int tid = threadIdx.x, w = tid >> 6, lane = tid & 63;
  int swzc = ((lane & 7) ^ (lane >> 3)) * 8;
  int wr = (w >> 2) * 64, wc = (w & 3) * 32, lrow = lane & 15, g = lane >> 4;
  int lcol = lane & 15, lr4 = (lane >> 4) * 4;
  int xcd = blockIdx.x & 7, bslot = blockIdx.x >> 3;

  for (int sl = bslot; sl < chunk; sl += 64) {
    int t = xcd * chunk + sl;
    if (t >= total) break;
    int ml = t >> 4, n = t & 15;
    int e = 0, mt = 0, Ne = 0;
    FIND_EXPERT(ml, cnt, e, mt, Ne);

    const u16* ap[2];
#pragma unroll
    for (int i = 0; i < 2; ++i) {
      int gr = mt * 128 + w * 8 + i * 64 + (lane >> 3);
      if (gr >= Ne) gr = Ne - 1;
      ap[i] = a_buf + ((size_t)e * T_ + gr) * H_ + swzc;
    }
    const u16* bp[2];
#pragma unroll
    for (int i = 0; i < 2; ++i) {
      int br = w * 8 + i * 64 + (lane >> 3);
      bp[i] = wb_out + (size_t)e * D_ * H_ + (size_t)(n * 128 + br) * H_ + swzc;
    }

    f32x4 acc[4][2];
#pragma unroll
    for (int m = 0; m < 4; ++m) { acc[m][0] = (f32x4){0,0,0,0}; acc[m][1] = (f32x4){0,0,0,0}; }

#pragma unroll
    for (int i = 0; i < 2; ++i) {
      gload16(ap[i], &As[0][(w * 8 + i * 64) * 64]);
      gload16(bp[i], &Bs[0][(w * 8 + i * 64) * 64]);
    }
    WAITVM0;
    __syncthreads();

    const int NT = H_ / BK;                        // 16
    for (int kt = 0; kt < NT; ++kt) {
      int cur = kt & 1;
      if (kt + 1 < NT) {
        int k = (kt + 1) * BK;
#pragma unroll
        for (int i = 0; i < 2; ++i) {
          gload16(ap[i] + k, &As[cur ^ 1][(w * 8 + i * 64) * 64]);
          gload16(bp[i] + k, &Bs[cur ^ 1][(w * 8 + i * 64) * 64]);
        }
      }
#pragma unroll
      for (int ks = 0; ks < 2; ++ks) {
        int ch = ks * 4 + g;
        s16x8 af[4], bf[2];
#pragma unroll
        for (int m = 0; m < 4; ++m) af[m] = *(const s16x8*)(&As[cur][slot(wr + m * 16 + lrow, ch)]);
#pragma unroll
        for (int s = 0; s < 2; ++s)  bf[s] = *(const s16x8*)(&Bs[cur][slot(wc + s * 16 + lrow, ch)]);
#pragma unroll
        for (int m = 0; m < 4; ++m)
#pragma unroll
          for (int s = 0; s < 2; ++s)
            acc[m][s] = __builtin_amdgcn_mfma_f32_16x16x32_bf16(af[m], bf[s], acc[m][s], 0, 0, 0);
      }
      WAITVM0;
      __syncthreads();
    }
    // epilogue: atomic accumulate (bias pre-filled by router)
#pragma unroll
    for (int m = 0; m < 4; ++m)
#pragma unroll
      for (int q = 0; q < 4; ++q) {
        int row = mt * 128 + wr + m * 16 + lr4 + q;
        if (row < Ne) {
          int p = lists[e * T_ + row];
          float gt = gates[p];
          int tok = p >> 1;
#pragma unroll
          for (int s = 0; s < 2; ++s)
            atomicAdd(&out[(size_t)tok * D_ + n * 128 + wc + s * 16 + lcol], gt * acc[m][s][q]);
        }
      }
  }
}

extern "C" void kernel_launch(void* const* d_in, const int* in_sizes, int n_in,
                              void* d_out, int out_size, void* d_ws, size_t ws_size,
                              hipStream_t stream)
{
  const float* x      = (const float*)d_in[0];
  const float* w_gate = (const float*)d_in[1];
  const float* w_in   = (const float*)d_in[2];
  const float* w_out  = (const float*)d_in[3];
  const float* bias   = (const float*)d_in[4];
  float* out = (float*)d_out;

  char* ws = (char*)d_ws;
  u16*   xb     = (u16*)(ws);
  u16*   a_buf  = (u16*)(ws + 8388608);
  u16*   wb_in  = (u16*)(ws + 41943040);
  u16*   wb_out = (u16*)(ws + 109051904);
  int*   lists  = (int*)(ws + 142606336);
  float* gates  = (float*)(ws + 142671872);
  int*   counts = (int*)(ws + 142688256);

  hipMemsetAsync(counts, 0, 32, stream);
  convert_kernel<<<2048, 256, 0, stream>>>(w_in,  wb_in,  WIN_ELEMS);
  convert_kernel<<<2048, 256, 0, stream>>>(w_out, wb_out, WOUT_ELEMS);
  router_kernel<<<T_, 256, 0, stream>>>(x, w_gate, bias, xb, lists, gates, counts, out);
  gemm1_kernel<<<512, 512, 0, stream>>>(xb, wb_in, lists, counts, a_buf);
  gemm2_kernel<<<512, 512, 0, stream>>>(a_buf, wb_out, lists, counts, gates, out);
}

// Round 14
// 239.582 us; speedup vs baseline: 1.3483x; 1.0331x over previous
//
#include <hip/hip_runtime.h>
#include <hip/hip_bf16.h>

#define E_    8
#define D_    2048
#define H_    1024
#define T_    2048   // B*L tokens
#define BK    64

using u16   = unsigned short;
using s16x8 = __attribute__((ext_vector_type(8))) short;
using f32x4 = __attribute__((ext_vector_type(4))) float;

#define WAITVM0 asm volatile("s_waitcnt vmcnt(0)" ::: "memory")

__device__ __forceinline__ short f2bf(float f) {
  __hip_bfloat16 h = __float2bfloat16(f);          // HW v_cvt (RNE)
  return __builtin_bit_cast(short, h);
}
// swizzled LDS slot (elem index) for (row, 8-elem chunk) in a [*][64] bf16 tile
__device__ __forceinline__ int slot(int r, int c) { return r * 64 + ((c ^ (r & 7)) << 3); }

__device__ __forceinline__ void gload16(const void* g, void* l) {
  __builtin_amdgcn_global_load_lds((const __attribute__((address_space(1))) void*)g,
                                   (__attribute__((address_space(3))) void*)l, 16, 0, 0);
}

// find (e, mt, Ne) for linear m-tile index ml (BM=128); registers only
#define FIND_EXPERT(ml, cnt, e, mt, Ne)                        \
  { int b_ = 0;                                                \
    _Pragma("unroll")                                          \
    for (int i_ = 0; i_ < E_; ++i_) {                          \
      int ti_ = (cnt[i_] + 127) >> 7;                          \
      if ((ml) >= b_ && (ml) < b_ + ti_) {                     \
        e = i_; mt = (ml) - b_; Ne = cnt[i_]; }                \
      b_ += ti_; } }

// ---------------- workspace layout (bytes) ----------------
// xb     : T*D bf16      =  8,388,608  @ 0
// a_buf  : E*T*H bf16    = 33,554,432  @ 8,388,608
// wb_in  : E*2H*D bf16   = 67,108,864  @ 41,943,040
// wb_out : E*D*H bf16    = 33,554,432  @ 109,051,904
// lists  : E*T int       =     65,536  @ 142,606,336
// gates  : T*K f32       =     16,384  @ 142,671,872
// counts : E int         =         32  @ 142,688,256

#define WIN_ELEMS  33554432   // E*2H*D
#define NCONV      3072       // convert blocks: (WIN+WOUT)/16384
#define SLICE      16384      // elems per convert block (4 iters x 256 thr x 16)

// FUSED prep: blocks [0,NCONV) stream-convert w_in/w_out fp32->bf16 (each block
// an independent 16K-elem slice, 4 independent unrolled iterations); blocks
// [NCONV, NCONV+T) run the per-token router (+ x->bf16 + out=bias prefill).
// Converts and router overlap across the machine instead of serializing.
__global__ __launch_bounds__(256) void prep_kernel(
    const float* __restrict__ x, const float* __restrict__ wg,
    const float* __restrict__ w_in, const float* __restrict__ w_out,
    const float* __restrict__ bias,
    u16* __restrict__ xb, u16* __restrict__ wb_in, u16* __restrict__ wb_out,
    int* __restrict__ lists, float* __restrict__ gates, int* __restrict__ counts,
    float* __restrict__ out)
{
  int tid = threadIdx.x;

  if (blockIdx.x < NCONV) {
    // ---- convert slice: 4 independent iterations, 16 loads in flight/thread
    int base = blockIdx.x * SLICE;
    const float* src; u16* dst;
    if (base < WIN_ELEMS) { src = w_in + base;               dst = wb_in + base; }
    else                  { src = w_out + (base - WIN_ELEMS); dst = wb_out + (base - WIN_ELEMS); }
#pragma unroll
    for (int it = 0; it < 4; ++it) {
      int o = it * 4096 + tid * 16;                // 4096 = 256 threads * 16 elems
      f32x4 a0 = *(const f32x4*)(src + o);
      f32x4 a1 = *(const f32x4*)(src + o + 4);
      f32x4 a2 = *(const f32x4*)(src + o + 8);
      f32x4 a3 = *(const f32x4*)(src + o + 12);
      s16x8 o0, o1;
      o0[0]=f2bf(a0.x); o0[1]=f2bf(a0.y); o0[2]=f2bf(a0.z); o0[3]=f2bf(a0.w);
      o0[4]=f2bf(a1.x); o0[5]=f2bf(a1.y); o0[6]=f2bf(a1.z); o0[7]=f2bf(a1.w);
      o1[0]=f2bf(a2.x); o1[1]=f2bf(a2.y); o1[2]=f2bf(a2.z); o1[3]=f2bf(a2.w);
      o1[4]=f2bf(a3.x); o1[5]=f2bf(a3.y); o1[6]=f2bf(a3.z); o1[7]=f2bf(a3.w);
      *(s16x8*)(dst + o)     = o0;
      *(s16x8*)(dst + o + 8) = o1;
    }
    return;
  }

  // ---- router for token t
  int t = blockIdx.x - NCONV;
  {
    const float* bp = bias + tid * 8;
    f32x4 b0 = *(const f32x4*)(bp), b1 = *(const f32x4*)(bp + 4);
    *(f32x4*)(out + (size_t)t * D_ + tid * 8)     = b0;
    *(f32x4*)(out + (size_t)t * D_ + tid * 8 + 4) = b1;
    if (t == 0 && tid == 0) out[(size_t)T_ * D_] = 0.0f;   // router aux loss
  }

  const float* xr = x + (size_t)t * D_;
  float acc[E_];
#pragma unroll
  for (int e = 0; e < E_; ++e) acc[e] = 0.f;
#pragma unroll
  for (int i = 0; i < D_ / 256; ++i) {
    int d = tid + 256 * i;
    float xv = xr[d];
    xb[(size_t)t * D_ + d] = (u16)f2bf(xv);
#pragma unroll
    for (int e = 0; e < E_; ++e) acc[e] += xv * wg[e * D_ + d];
  }
#pragma unroll
  for (int off = 32; off >= 1; off >>= 1)
#pragma unroll
    for (int e = 0; e < E_; ++e) acc[e] += __shfl_down(acc[e], off);

  __shared__ float red[4][E_];
  int w = tid >> 6, lane = tid & 63;
  if (lane == 0)
#pragma unroll
    for (int e = 0; e < E_; ++e) red[w][e] = acc[e];
  __syncthreads();
  if (tid == 0) {
    float v0 = -1e30f, v1 = -1e30f; int e0 = 0, e1 = 0;
#pragma unroll
    for (int e = 0; e < E_; ++e) {
      float v = red[0][e] + red[1][e] + red[2][e] + red[3][e];
      if (v > v0)      { v1 = v0; e1 = e0; v0 = v; e0 = e; }
      else if (v > v1) { v1 = v;  e1 = e; }
    }
    float g1 = expf(v1 - v0);
    float inv = 1.f / (1.f + g1);
    float g0 = inv; g1 *= inv;
    int s0 = atomicAdd(&counts[e0], 1);
    lists[e0 * T_ + s0] = t * 2 + 0;
    gates[t * 2 + 0] = g0;
    int s1 = atomicAdd(&counts[e1], 1);
    lists[e1 * T_ + s1] = t * 2 + 1;
    gates[t * 2 + 1] = g1;
  }
}

// grouped GEMM1 + SiLU-GLU, all-bf16 gload_lds staging (R13 verbatim).
// Tile: 128 token-rows x 128 B-rows (64 h1 + 64 h2 -> 64 h-cols).
// 8 waves (2m x 4n), wave = 64 rows x 32 B-cols. 64 KB LDS -> 2 blocks/CU.
__global__ __launch_bounds__(512, 2) void gemm1_kernel(
    const u16* __restrict__ xb, const u16* __restrict__ wb_in,
    const int* __restrict__ lists, const int* __restrict__ counts,
    u16* __restrict__ a_buf)
{
  __shared__ __align__(16) u16 As[2][128 * 64];   // 32 KB
  __shared__ __align__(16) u16 Bs[2][128 * 64];   // 32 KB

  int cnt[E_];
#pragma unroll
  for (int i = 0; i < E_; ++i) cnt[i] = counts[i];
  int mt_total = 0;
#pragma unroll
  for (int i = 0; i < E_; ++i) mt_total += (cnt[i] + 127) >> 7;
  int total = mt_total * 16;                      // 16 n-tiles of 64 h-cols
  int chunk = (total + 7) >> 3;

  int tid = threadIdx.x, w = tid >> 6, lane = tid & 63;
  int swzc = ((lane & 7) ^ (lane >> 3)) * 8;      // pre-swizzled source chunk
  int wr = (w >> 2) * 64, wc = (w & 3) * 32, lrow = lane & 15, g = lane >> 4;
  int lcol = lane & 15, lr4 = (lane >> 4) * 4;
  int xcd = blockIdx.x & 7, bslot = blockIdx.x >> 3;

  for (int sl = bslot; sl < chunk; sl += 64) {
    int t = xcd * chunk + sl;
    if (t >= total) break;
    int ml = t >> 4, n = t & 15;
    int e = 0, mt = 0, Ne = 0;
    FIND_EXPERT(ml, cnt, e, mt, Ne);

    const u16* ap[2];
#pragma unroll
    for (int i = 0; i < 2; ++i) {
      int gr = mt * 128 + w * 8 + i * 64 + (lane >> 3);
      if (gr >= Ne) gr = Ne - 1;
      ap[i] = xb + (size_t)(lists[e * T_ + gr] >> 1) * D_ + swzc;
    }
    const u16* bp[2];
#pragma unroll
    for (int i = 0; i < 2; ++i) {
      int br = w * 8 + i * 64 + (lane >> 3);
      int o = n * 64 + ((br >> 4) & 1) * H_ + (br >> 5) * 16 + (br & 15);
      bp[i] = wb_in + (size_t)e * (2 * H_) * D_ + (size_t)o * D_ + swzc;
    }

    f32x4 acc[4][2];
#pragma unroll
    for (int m = 0; m < 4; ++m) { acc[m][0] = (f32x4){0,0,0,0}; acc[m][1] = (f32x4){0,0,0,0}; }

#pragma unroll
    for (int i = 0; i < 2; ++i) {
      gload16(ap[i], &As[0][(w * 8 + i * 64) * 64]);
      gload16(bp[i], &Bs[0][(w * 8 + i * 64) * 64]);
    }
    WAITVM0;
    __syncthreads();

    const int NT = D_ / BK;                        // 32
    for (int kt = 0; kt < NT; ++kt) {
      int cur = kt & 1;
      if (kt + 1 < NT) {
        int k = (kt + 1) * BK;
#pragma unroll
        for (int i = 0; i < 2; ++i) {
          gload16(ap[i] + k, &As[cur ^ 1][(w * 8 + i * 64) * 64]);
          gload16(bp[i] + k, &Bs[cur ^ 1][(w * 8 + i * 64) * 64]);
        }
      }
#pragma unroll
      for (int ks = 0; ks < 2; ++ks) {
        int ch = ks * 4 + g;
        s16x8 af[4], bf[2];
#pragma unroll
        for (int m = 0; m < 4; ++m) af[m] = *(const s16x8*)(&As[cur][slot(wr + m * 16 + lrow, ch)]);
#pragma unroll
        for (int s = 0; s < 2; ++s)  bf[s] = *(const s16x8*)(&Bs[cur][slot(wc + s * 16 + lrow, ch)]);
#pragma unroll
        for (int m = 0; m < 4; ++m)
#pragma unroll
          for (int s = 0; s < 2; ++s)
            acc[m][s] = __builtin_amdgcn_mfma_f32_16x16x32_bf16(af[m], bf[s], acc[m][s], 0, 0, 0);
      }
      WAITVM0;
      __syncthreads();
    }
#pragma unroll
    for (int m = 0; m < 4; ++m)
#pragma unroll
      for (int q = 0; q < 4; ++q) {
        int row = mt * 128 + wr + m * 16 + lr4 + q;
        if (row < Ne) {
          float h1 = acc[m][0][q], h2 = acc[m][1][q];
          float a = (h1 / (1.f + __expf(-h1))) * h2;
          a_buf[((size_t)e * T_ + row) * H_ + n * 64 + (w & 3) * 16 + lcol] = (u16)f2bf(a);
        }
      }
  }
}

// grouped GEMM2: out[t] += gate * (a_row . wb_out^T), all-bf16 gloads (R13).
// Tile: 128 rows x 128 d-cols, 8 waves (2m x 4n) of 64x32, 64 KB LDS.
__global__ __launch_bounds__(512, 2) void gemm2_kernel(
    const u16* __restrict__ a_buf, const u16* __restrict__ wb_out,
    const int* __restrict__ lists, const int* __restrict__ counts,
    const float* __restrict__ gates, float* __restrict__ out)
{
  __shared__ __align__(16) u16 As[2][128 * 64];
  __shared__ __align__(16) u16 Bs[2][128 * 64];

  int cnt[E_];
#pragma unroll
  for (int i = 0; i < E_; ++i) cnt[i] = counts[i];
  int mt_total = 0;
#pragma unroll
  for (int i = 0; i < E_; ++i) mt_total += (cnt[i] + 127) >> 7;
  int total = mt_total * 16;                      // 16 n-tiles of 128 d-cols
  int chunk = (total + 7) >> 3;

  int tid = threadIdx.x, w = tid >> 6, lane = tid & 63;
  int swzc = ((lane & 7) ^ (lane >> 3)) * 8;
  int wr = (w >> 2) * 64, wc = (w & 3) * 32, lrow = lane & 15, g = lane >> 4;
  int lcol = lane & 15, lr4 = (lane >> 4) * 4;
  int xcd = blockIdx.x & 7, bslot = blockIdx.x >> 3;

  for (int sl = bslot; sl < chunk; sl += 64) {
    int t = xcd * chunk + sl;
    if (t >= total) break;
    int ml = t >> 4, n = t & 15;
    int e = 0, mt = 0, Ne = 0;
    FIND_EXPERT(ml, cnt, e, mt, Ne);

    const u16* ap[2];
#pragma unroll
    for (int i = 0; i < 2; ++i) {
      int gr = mt * 128 + w * 8 + i * 64 + (lane >> 3);
      if (gr >= Ne) gr = Ne - 1;
      ap[i] = a_buf + ((size_t)e * T_ + gr) * H_ + swzc;
    }
    const u16* bp[2];
#pragma unroll
    for (int i = 0; i < 2; ++i) {
      int br = w * 8 + i * 64 + (lane >> 3);
      bp[i] = wb_out + (size_t)e * D_ * H_ + (size_t)(n * 128 + br) * H_ + swzc;
    }

    f32x4 acc[4][2];
#pragma unroll
    for (int m = 0; m < 4; ++m) { acc[m][0] = (f32x4){0,0,0,0}; acc[m][1] = (f32x4){0,0,0,0}; }

#pragma unroll
    for (int i = 0; i < 2; ++i) {
      gload16(ap[i], &As[0][(w * 8 + i * 64) * 64]);
      gload16(bp[i], &Bs[0][(w * 8 + i * 64) * 64]);
    }
    WAITVM0;
    __syncthreads();

    const int NT = H_ / BK;                        // 16
    for (int kt = 0; kt < NT; ++kt) {
      int cur = kt & 1;
      if (kt + 1 < NT) {
        int k = (kt + 1) * BK;
#pragma unroll
        for (int i = 0; i < 2; ++i) {
          gload16(ap[i] + k, &As[cur ^ 1][(w * 8 + i * 64) * 64]);
          gload16(bp[i] + k, &Bs[cur ^ 1][(w * 8 + i * 64) * 64]);
        }
      }
#pragma unroll
      for (int ks = 0; ks < 2; ++ks) {
        int ch = ks * 4 + g;
        s16x8 af[4], bf[2];
#pragma unroll
        for (int m = 0; m < 4; ++m) af[m] = *(const s16x8*)(&As[cur][slot(wr + m * 16 + lrow, ch)]);
#pragma unroll
        for (int s = 0; s < 2; ++s)  bf[s] = *(const s16x8*)(&Bs[cur][slot(wc + s * 16 + lrow, ch)]);
#pragma unroll
        for (int m = 0; m < 4; ++m)
#pragma unroll
          for (int s = 0; s < 2; ++s)
            acc[m][s] = __builtin_amdgcn_mfma_f32_16x16x32_bf16(af[m], bf[s], acc[m][s], 0, 0, 0);
      }
      WAITVM0;
      __syncthreads();
    }
#pragma unroll
    for (int m = 0; m < 4; ++m)
#pragma unroll
      for (int q = 0; q < 4; ++q) {
        int row = mt * 128 + wr + m * 16 + lr4 + q;
        if (row < Ne) {
          int p = lists[e * T_ + row];
          float gt = gates[p];
          int tok = p >> 1;
#pragma unroll
          for (int s = 0; s < 2; ++s)
            atomicAdd(&out[(size_t)tok * D_ + n * 128 + wc + s * 16 + lcol], gt * acc[m][s][q]);
        }
      }
  }
}

extern "C" void kernel_launch(void* const* d_in, const int* in_sizes, int n_in,
                              void* d_out, int out_size, void* d_ws, size_t ws_size,
                              hipStream_t stream)
{
  const float* x      = (const float*)d_in[0];
  const float* w_gate = (const float*)d_in[1];
  const float* w_in   = (const float*)d_in[2];
  const float* w_out  = (const float*)d_in[3];
  const float* bias   = (const float*)d_in[4];
  float* out = (float*)d_out;

  char* ws = (char*)d_ws;
  u16*   xb     = (u16*)(ws);
  u16*   a_buf  = (u16*)(ws + 8388608);
  u16*   wb_in  = (u16*)(ws + 41943040);
  u16*   wb_out = (u16*)(ws + 109051904);
  int*   lists  = (int*)(ws + 142606336);
  float* gates  = (float*)(ws + 142671872);
  int*   counts = (int*)(ws + 142688256);

  hipMemsetAsync(counts, 0, 32, stream);
  prep_kernel<<<NCONV + T_, 256, 0, stream>>>(x, w_gate, w_in, w_out, bias,
                                              xb, wb_in, wb_out, lists, gates, counts, out);
  gemm1_kernel<<<512, 512, 0, stream>>>(xb, wb_in, lists, counts, a_buf);
  gemm2_kernel<<<512, 512, 0, stream>>>(a_buf, wb_out, lists, counts, gates, out);
}